// Round 9
// baseline (280.391 us; speedup 1.0000x reference)
//
#include <hip/hip_runtime.h>

#define N_NODES   50000
#define N_EDGES   800000
#define DIM       96
#define N_GRAPHS  128
#define OUT_DIM   10
#define NPAD      50048        // 782 * 64 rows (gemm grid coverage)
#define ZROW      N_NODES      // dedicated all-zero row for bucket padding
#define CAP       64           // per-node bucket capacity (Poisson(16) tail ~1e-20)
#define LPAD      104          // LDS agg row stride: 208B = 13x16B (b128-aligned rows)

#define EBLK      ((N_EDGES + 1023) / 1024)           // 782 edge blocks, 1024 edges each
#define CAST_NB   ((N_NODES * 12 + 255) / 256)        // 2344
#define CONV_NB   ((3 * DIM * 2 * DIM + 255) / 256)   // 216

typedef __attribute__((ext_vector_type(8))) short          short8;
typedef __attribute__((ext_vector_type(8))) unsigned short u16x8;
typedef __attribute__((ext_vector_type(4))) float          f32x4;
typedef __attribute__((ext_vector_type(2))) float          f32x2;

__device__ __forceinline__ float b2f(unsigned short u) {
    union { unsigned int i; float f; } v; v.i = ((unsigned int)u) << 16; return v.f;
}
__device__ __forceinline__ unsigned short f2b(float f) {   // round-to-nearest-even
    union { float f; unsigned int i; } v; v.f = f;
    unsigned int u = v.i;
    return (unsigned short)((u + 0x7fffu + ((u >> 16) & 1u)) >> 16);
}

// ---------------------------------------------------------------------------
// OCP e4m3 shadow codec.  Shadow stores h*0.25 (h_max ~1024 -> 256 < 448 max
// finite).  HW path: v_cvt_pk_f32_fp8 / v_cvt_pk_fp8_f32 (1 inst / 2 elems) —
// confirmed r6/r7.  SW fallback kept, guarded.
// ---------------------------------------------------------------------------
#if __has_builtin(__builtin_amdgcn_cvt_pk_f32_fp8) && __has_builtin(__builtin_amdgcn_cvt_pk_fp8_f32)
#define HW_FP8 1
#endif

__device__ __forceinline__ float d8s(unsigned int b) {     // SW decode (fallback)
    const unsigned int t = b & 0x7fu;
    union { unsigned int i; float f; } v;
    v.i = ((b & 0x80u) << 24) | ((t << 20) + (120u << 23));
    float sub = (float)(int)t * 0.001953125f;              // subnormal m*2^-9
    if (b & 0x80u) sub = -sub;
    return (t < 8u) ? sub : v.f;
}
__device__ __forceinline__ unsigned int e8s(float f) {     // SW encode (fallback)
    union { float f; unsigned int i; } v; v.f = f;
    const unsigned int u = v.i;
    const unsigned int s = (u >> 24) & 0x80u;
    const float af = fabsf(f);
    if (af < 0.015625f) {                                  // subnormal
        int mi = (int)(af * 512.f + 0.5f);
        return s | (unsigned int)(mi > 7 ? 7 : mi);
    }
    const unsigned int r = (u & 0x7fffffffu) + 0x0007ffffu + ((u >> 20) & 1u);
    const int ee = (int)(r >> 23) - 120;
    if (ee > 15) return s | 0x7eu;                         // clamp to 448
    return s | ((unsigned int)ee << 3) | ((r >> 20) & 7u);
}

template<bool HI> __device__ __forceinline__ f32x2 dec_pk(unsigned int d) {
#ifdef HW_FP8
    return __builtin_amdgcn_cvt_pk_f32_fp8((int)d, HI);
#else
    const unsigned int w = HI ? (d >> 16) : (d & 0xffffu);
    f32x2 r; r[0] = d8s(w & 0xffu); r[1] = d8s(w >> 8);
    return r;
#endif
}
template<bool HI> __device__ __forceinline__ unsigned int enc_pk(float a, float b,
                                                                 unsigned int old) {
#ifdef HW_FP8
    return (unsigned int)__builtin_amdgcn_cvt_pk_fp8_f32(a, b, (int)old, HI);
#else
    const unsigned int p = e8s(a) | (e8s(b) << 8);
    return HI ? ((old & 0x0000ffffu) | (p << 16)) : ((old & 0xffff0000u) | p);
#endif
}

// ---------------------------------------------------------------------------
// Zero the per-node degree counters (workspace is poisoned each run; must
// precede the direct-scatter atomics — separate launch = stream-ordered).
// ---------------------------------------------------------------------------
__global__ __launch_bounds__(256) void zero_cnt(int* __restrict__ deg)
{
    const int n = blockIdx.x * 256 + threadIdx.x;
    if (n < N_NODES) deg[n] = 0;
}

// ---------------------------------------------------------------------------
// Fused {DIRECT edge scatter | cast x -> bf16 + fp8 shadow | build Bt | zero-
// row + gr init}.  THIS ROUND: the two-pass binning (800k LDS atomics +
// 800k scattered binned-writes + 9.6MB re-read + 800k more LDS atomics +
// 800k scattered csrc-writes) is replaced by ONE pass of per-node global
// returning atomicAdd + direct csrc write.  Regime distinction vs the old
// "same-address atomics ~120ns" finding: that was 391 HOT counters (~2k
// contenders each); per-node counters are 50k SPREAD addresses (~16
// contenders) — pipelined, no hot line.  Edge blocks: 782 x 1024 edges
// (6x the old 128-block parallelism; no per-block LDS slice state needed).
// ---------------------------------------------------------------------------
__global__ __launch_bounds__(256) void prep_pass1(
    const float* __restrict__ x,  const float* __restrict__ W1,
    const float* __restrict__ W2, const int* __restrict__ src,
    const int* __restrict__ dst,  unsigned short* __restrict__ harr,
    unsigned short* __restrict__ harrB,
    unsigned char* __restrict__ shA, unsigned char* __restrict__ shB,
    unsigned short* __restrict__ Bt, int* __restrict__ csrc,
    int* __restrict__ deg, float* __restrict__ gr)
{
    const int b = blockIdx.x;
    const int t = threadIdx.x;

    if (b < EBLK) {
        const int e0 = b * 1024 + t * 4;      // N_EDGES % 4 == 0
        if (e0 < N_EDGES) {
            const int4 d4 = *(const int4*)(dst + e0);
            const int4 s4 = *(const int4*)(src + e0);
            const int p0 = atomicAdd(&deg[d4.x], 1);
            const int p1 = atomicAdd(&deg[d4.y], 1);
            const int p2 = atomicAdd(&deg[d4.z], 1);
            const int p3 = atomicAdd(&deg[d4.w], 1);
            if (p0 < CAP) csrc[(size_t)d4.x * CAP + p0] = s4.x;
            if (p1 < CAP) csrc[(size_t)d4.y * CAP + p1] = s4.y;
            if (p2 < CAP) csrc[(size_t)d4.z * CAP + p2] = s4.z;
            if (p3 < CAP) csrc[(size_t)d4.w * CAP + p3] = s4.w;
        }
    } else if (b < EBLK + CAST_NB) {
        const int tid = (b - EBLK) * 256 + t;         // one per 8 cols
        if (tid >= N_NODES * 12) return;
        const int node = tid / 12;
        const int c    = (tid - node * 12) * 8;
        const float4 v0 = *(const float4*)(x + (size_t)node * DIM + c);
        const float4 v1 = *(const float4*)(x + (size_t)node * DIM + c + 4);
        u16x8 o;
        o[0] = f2b(v0.x); o[1] = f2b(v0.y); o[2] = f2b(v0.z); o[3] = f2b(v0.w);
        o[4] = f2b(v1.x); o[5] = f2b(v1.y); o[6] = f2b(v1.z); o[7] = f2b(v1.w);
        *(u16x8*)(harr + (size_t)node * DIM + c) = o;
        // fp8 shadow of x (gather input, layer 0): stores x*0.25
        unsigned int da = 0u, db = 0u;
        da = enc_pk<false>(v0.x * 0.25f, v0.y * 0.25f, da);
        da = enc_pk<true >(v0.z * 0.25f, v0.w * 0.25f, da);
        db = enc_pk<false>(v1.x * 0.25f, v1.y * 0.25f, db);
        db = enc_pk<true >(v1.z * 0.25f, v1.w * 0.25f, db);
        uint2 ob; ob.x = da; ob.y = db;
        *(uint2*)(shA + (size_t)node * 96 + c) = ob;
    } else if (b < EBLK + CAST_NB + CONV_NB) {
        const int idx = (b - EBLK - CAST_NB) * 256 + t;   // Bt[l][n][k]
        if (idx >= 3 * DIM * 2 * DIM) return;
        const int l   = idx / (DIM * 2 * DIM);
        const int rem = idx - l * (DIM * 2 * DIM);
        const int n   = rem / (2 * DIM);
        const int k   = rem - n * (2 * DIM);
        const float v = (k < DIM) ? W1[(size_t)l * DIM * DIM + k * DIM + n]
                                  : W2[(size_t)l * DIM * DIM + (k - DIM) * DIM + n];
        Bt[idx] = f2b(v);
    } else {
        // zero-row init + gr zeroing
        if (t < 24) {
            u16x8 z;
#pragma unroll
            for (int i = 0; i < 8; i++) z[i] = 0;
            unsigned short* p = (t < 12) ? (harr  + (size_t)ZROW * DIM + t * 8)
                                         : (harrB + (size_t)ZROW * DIM + (t - 12) * 8);
            *(u16x8*)p = z;
        } else if (t < 48) {
            const int i = t - 24;                 // 0..23: 12 x 8B per shadow row
            uint2 z; z.x = 0u; z.y = 0u;
            unsigned char* p = (i < 12) ? (shA + (size_t)ZROW * 96 + i * 8)
                                        : (shB + (size_t)ZROW * 96 + (i - 12) * 8);
            *(uint2*)p = z;
        }
        float4* g4 = (float4*)gr;                 // 128*96 f32 = 3072 float4
#pragma unroll
        for (int i = 0; i < 12; i++) g4[t * 12 + i] = make_float4(0.f, 0.f, 0.f, 0.f);
    }
}

// ---------------------------------------------------------------------------
// Pad each bucket with ZROW entries to a multiple of 4 and finalize deg
// (padded count, in place).  Gather then runs full 4-row batches only.
// ---------------------------------------------------------------------------
__global__ __launch_bounds__(256) void pad_buckets(int* __restrict__ deg,
                                                   int* __restrict__ csrc)
{
    const int n = blockIdx.x * 256 + threadIdx.x;
    if (n >= N_NODES) return;
    const int dn = min(deg[n], CAP);
    const int dp = (dn + 3) & ~3;                 // pad to multiple of 4 (<= CAP)
    int* __restrict__ bkt = csrc + (size_t)n * CAP;
    for (int p = dn; p < dp; p++) bkt[p] = ZROW;
    deg[n] = dp;
}

// ---------------------------------------------------------------------------
// Fused layer, 384 threads, template<LAST> (unchanged from r7 — measured
// 44.4us/layer, FETCH 37.5MB ~= compulsory per-XCD fills).  Gather reads the
// fp8 shadow (96 B/row, 6 lanes x one 16B load) with HW cvt_pk_f32_fp8
// decode.  Shadow holds h*0.25; x4 applied once at LDS write.  Phase 2:
// mfma_f32_16x16x32_bf16, A-frag A[m=lane&15][k=quad*8+j], C/D col=lane&15,
// row=quad*4+reg (m89-verified).  LAST fuses graph pooling: run-length merge
// by graph id then spread atomicAdd into gr[128][96].
// ---------------------------------------------------------------------------
#define LOAD4(x0,x1,x2,x3,base) do {                                        \
    const int4 sI = *(const int4*)(bkt + (base));                           \
    x0 = *(const uint4*)(hb + (size_t)sI.x * 96);                           \
    x1 = *(const uint4*)(hb + (size_t)sI.y * 96);                           \
    x2 = *(const uint4*)(hb + (size_t)sI.z * 96);                           \
    x3 = *(const uint4*)(hb + (size_t)sI.w * 96);                           \
} while (0)

#define ACCD(dw, b0) do {                                                   \
    const f32x2 lo_ = dec_pk<false>(dw);                                    \
    const f32x2 hi_ = dec_pk<true >(dw);                                    \
    a[(b0) + 0] += lo_[0]; a[(b0) + 1] += lo_[1];                           \
    a[(b0) + 2] += hi_[0]; a[(b0) + 3] += hi_[1];                           \
} while (0)
#define ACC1(vv) do { ACCD(vv.x, 0); ACCD(vv.y, 4); ACCD(vv.z, 8); ACCD(vv.w, 12); } while (0)
#define ACC4(x0,x1,x2,x3) do { ACC1(x0); ACC1(x1); ACC1(x2); ACC1(x3); } while (0)

template<bool LAST>
__global__ __launch_bounds__(384) void gnn_layer(
    const unsigned short* __restrict__ harr, const int* __restrict__ deg,
    const int* __restrict__ csrc, const unsigned short* __restrict__ Btl,
    unsigned short* __restrict__ hout,
    const unsigned char* __restrict__ shIn, unsigned char* __restrict__ shOut,
    const int* __restrict__ batch, float* __restrict__ gr)
{
    __shared__ unsigned short aggLds[64][LPAD];
    __shared__ int batchLds[64];
    const int t       = threadIdx.x;
    const int rowBase = blockIdx.x * 64;

    const int lane = t & 63;
    const int w    = t >> 6;    // 0..5 col tile
    const int m    = lane & 15;
    const int q    = lane >> 4;

    if constexpr (LAST) {
        if (t < 64)
            batchLds[t] = (rowBase + t < N_NODES) ? batch[rowBase + t] : -1;
    }

    // hoisted B fragments (overlap with gather)
    short8 bfrag[6];
#pragma unroll
    for (int s = 0; s < 6; s++)
        bfrag[s] = *(const short8*)(Btl + (size_t)(w * 16 + m) * (2 * DIM) + s * 32 + q * 8);

    // ---- phase 1: gather from fp8 shadow (6 lanes x 16B = one 96B row) ----
    {
        const int r    = t / 6;          // 0..63
        const int sub  = t - r * 6;      // 0..5
        const int node = rowBase + r;
        const int off  = sub * 16;       // 16 cols = 16 B (fp8) = 16 elems (LDS)

        float a[16];
#pragma unroll
        for (int i = 0; i < 16; i++) a[i] = 0.f;

        if (node < N_NODES) {
            const int nb = deg[node] >> 2;          // padded: full batches only
            const int* __restrict__ bkt = csrc + (size_t)node * CAP;
            const unsigned char* __restrict__ hb = shIn + off;

            uint4 va0, va1, va2, va3;   // set A
            uint4 wa0, wa1, wa2, wa3;   // set B

            if (nb > 0) {
                LOAD4(va0, va1, va2, va3, 0);
                int b = 1;
                for (; b + 1 < nb; b += 2) {
                    LOAD4(wa0, wa1, wa2, wa3, b * 4);
                    ACC4(va0, va1, va2, va3);
                    LOAD4(va0, va1, va2, va3, (b + 1) * 4);
                    ACC4(wa0, wa1, wa2, wa3);
                }
                if (b < nb) {
                    LOAD4(wa0, wa1, wa2, wa3, b * 4);
                    ACC4(va0, va1, va2, va3);
                    ACC4(wa0, wa1, wa2, wa3);
                } else {
                    ACC4(va0, va1, va2, va3);
                }
            }
        }

        u16x8 o0, o1;
#pragma unroll
        for (int i = 0; i < 8; i++) {
            o0[i] = f2b(a[i] * 4.f);            // undo the /4 shadow scale once
            o1[i] = f2b(a[i + 8] * 4.f);
        }
        *(u16x8*)(&aggLds[r][off])     = o0;
        *(u16x8*)(&aggLds[r][off + 8]) = o1;
    }
    __syncthreads();

    // ---- phase 2: MFMA (all accs first; aggLds still holds the agg tile) ----
    f32x4 accv[4];
#pragma unroll
    for (int r = 0; r < 4; r++) {
        const int rb = rowBase + r * 16;
        f32x4 acc = {0.f, 0.f, 0.f, 0.f};
        const unsigned short* ah = harr + (size_t)(rb + m) * DIM + q * 8;
#pragma unroll
        for (int s = 0; s < 3; s++) {
            const short8 af = *(const short8*)(ah + s * 32);
            acc = __builtin_amdgcn_mfma_f32_16x16x32_bf16(af, bfrag[s], acc, 0, 0, 0);
        }
#pragma unroll
        for (int s = 0; s < 3; s++) {
            const short8 af = *(const short8*)(&aggLds[r * 16 + m][s * 32 + q * 8]);
            acc = __builtin_amdgcn_mfma_f32_16x16x32_bf16(af, bfrag[s + 3], acc, 0, 0, 0);
        }
        accv[r] = acc;
    }

    if constexpr (LAST) {
        // ---- fused pooling: run-length merge by graph, then atomicAdd ----
        const int col = w * 16 + m;
        int   curg = -1;
        float sum  = 0.f;
#pragma unroll
        for (int r = 0; r < 4; r++) {
#pragma unroll
            for (int i = 0; i < 4; i++) {
                const int g = batchLds[r * 16 + q * 4 + i];
                const float v = fmaxf(accv[r][i], 0.f);
                if (g < 0) {
                    if (curg >= 0) { atomicAdd(&gr[curg * DIM + col], sum); curg = -1; }
                } else if (g != curg) {
                    if (curg >= 0) atomicAdd(&gr[curg * DIM + col], sum);
                    curg = g; sum = v;
                } else {
                    sum += v;
                }
            }
        }
        if (curg >= 0) atomicAdd(&gr[curg * DIM + col], sum);
    } else {
        __syncthreads();        // all aggLds reads done; safe to overwrite

        // ---- epilogue: acc -> LDS -> coalesced bf16 + fp8 shadow stores ----
#pragma unroll
        for (int r = 0; r < 4; r++)
#pragma unroll
            for (int i = 0; i < 4; i++)
                aggLds[r * 16 + q * 4 + i][w * 16 + m] = f2b(fmaxf(accv[r][i], 0.f));
        __syncthreads();

#pragma unroll
        for (int k = 0; k < 2; k++) {
            const int idx = t + k * 384;     // 768 chunks: 64 rows x 12 x 16B
            const int row = idx / 12;
            const int ch  = idx - row * 12;
            const int grow = rowBase + row;
            if (grow < N_NODES)
                *(u16x8*)(hout + (size_t)grow * DIM + ch * 8)
                    = *(const u16x8*)(&aggLds[row][ch * 8]);
        }
        {
            const int row  = t / 6;          // 384 chunks: 64 rows x 6 x 16 cols
            const int ch   = t - row * 6;
            const int grow = rowBase + row;
            if (grow < N_NODES) {
                const u16x8 h0 = *(const u16x8*)(&aggLds[row][ch * 16]);
                const u16x8 h1 = *(const u16x8*)(&aggLds[row][ch * 16 + 8]);
                unsigned int d0 = 0u, d1 = 0u, d2 = 0u, d3 = 0u;
                d0 = enc_pk<false>(b2f(h0[0]) * 0.25f, b2f(h0[1]) * 0.25f, d0);
                d0 = enc_pk<true >(b2f(h0[2]) * 0.25f, b2f(h0[3]) * 0.25f, d0);
                d1 = enc_pk<false>(b2f(h0[4]) * 0.25f, b2f(h0[5]) * 0.25f, d1);
                d1 = enc_pk<true >(b2f(h0[6]) * 0.25f, b2f(h0[7]) * 0.25f, d1);
                d2 = enc_pk<false>(b2f(h1[0]) * 0.25f, b2f(h1[1]) * 0.25f, d2);
                d2 = enc_pk<true >(b2f(h1[2]) * 0.25f, b2f(h1[3]) * 0.25f, d2);
                d3 = enc_pk<false>(b2f(h1[4]) * 0.25f, b2f(h1[5]) * 0.25f, d3);
                d3 = enc_pk<true >(b2f(h1[6]) * 0.25f, b2f(h1[7]) * 0.25f, d3);
                uint4 ob; ob.x = d0; ob.y = d1; ob.z = d2; ob.w = d3;
                *(uint4*)(shOut + (size_t)grow * 96 + ch * 16) = ob;
            }
        }
    }
}

// ---------------------------------------------------------------------------
// Tiny classifier on the pooled gr[128][96] (pooling fused into layer 3).
// ---------------------------------------------------------------------------
__global__ __launch_bounds__(128) void classify(
    const float* __restrict__ gr,
    const float* __restrict__ cw1, const float* __restrict__ cb1,
    const float* __restrict__ cw2, const float* __restrict__ cb2,
    float* __restrict__ out)
{
    const int g = blockIdx.x;
    const int t = threadIdx.x;

    __shared__ float grs[DIM];
    __shared__ float hid[DIM];

    if (t < DIM) grs[t] = gr[g * DIM + t];
    __syncthreads();

    if (t < DIM) {
        float hsum = cb1[t];
#pragma unroll 8
        for (int k = 0; k < DIM; k++) hsum += grs[k] * cw1[k * DIM + t];
        hid[t] = fmaxf(hsum, 0.f);
    }
    __syncthreads();

    if (t < OUT_DIM) {
        float o = cb2[t];
#pragma unroll 8
        for (int k = 0; k < DIM; k++) o += hid[k] * cw2[k * OUT_DIM + t];
        out[g * OUT_DIM + t] = o;
    }
}

// ---------------------------------------------------------------------------
extern "C" void kernel_launch(void* const* d_in, const int* in_sizes, int n_in,
                              void* d_out, int out_size, void* d_ws, size_t ws_size,
                              hipStream_t stream)
{
    const float* x     = (const float*)d_in[0];
    const int*   ei    = (const int*)  d_in[1];
    const int*   batch = (const int*)  d_in[2];
    const float* W1    = (const float*)d_in[3];
    const float* W2    = (const float*)d_in[4];
    const float* cw1   = (const float*)d_in[5];
    const float* cb1   = (const float*)d_in[6];
    const float* cw2   = (const float*)d_in[7];
    const float* cb2   = (const float*)d_in[8];
    float*       out   = (float*)d_out;

    const int* src = ei;             // edge_index[0]
    const int* dst = ei + N_EDGES;   // edge_index[1]

    // workspace layout (16B-aligned at each boundary)
    unsigned short* bufA = (unsigned short*)d_ws;          // [NPAD,96] bf16
    unsigned short* bufB = bufA + (size_t)NPAD * DIM;      // [NPAD,96] bf16
    unsigned short* Bt   = bufB + (size_t)NPAD * DIM;      // [3,96,192] bf16
    int*   csrc   = (int*)(Bt + 3 * DIM * 2 * DIM);        // [N*CAP]
    int*   deg    = csrc + (size_t)N_NODES * CAP;          // [N] (counters, then padded deg)
    unsigned char* shA = (unsigned char*)(deg + N_NODES);  // [(N+1)*96] fp8
    unsigned char* shB = shA + (size_t)(N_NODES + 1) * 96; // [(N+1)*96] fp8
    float* gr = (float*)(shB + (size_t)(N_NODES + 1) * 96);// [128,96] f32

    zero_cnt<<<(N_NODES + 255) / 256, 256, 0, stream>>>(deg);
    prep_pass1<<<EBLK + CAST_NB + CONV_NB + 1, 256, 0, stream>>>(
        x, W1, W2, src, dst, bufA, bufB, shA, shB, Bt, csrc, deg, gr);
    pad_buckets<<<(N_NODES + 255) / 256, 256, 0, stream>>>(deg, csrc);

    gnn_layer<false><<<NPAD / 64, 384, 0, stream>>>(bufA, deg, csrc, Bt,
                                                    bufB, shA, shB, batch, gr);
    gnn_layer<false><<<NPAD / 64, 384, 0, stream>>>(bufB, deg, csrc,
                                                    Bt + (size_t)DIM * 2 * DIM,
                                                    bufA, shB, shA, batch, gr);
    gnn_layer<true><<<NPAD / 64, 384, 0, stream>>>(bufA, deg, csrc,
                                                   Bt + (size_t)2 * DIM * 2 * DIM,
                                                   bufB, shA, shB, batch, gr);

    classify<<<N_GRAPHS, 128, 0, stream>>>(gr, cw1, cb1, cw2, cb2, out);
}

// Round 10
// 241.652 us; speedup vs baseline: 1.1603x; 1.1603x over previous
//
#include <hip/hip_runtime.h>

#define N_NODES   50000
#define N_EDGES   800000
#define DIM       96
#define N_GRAPHS  128
#define OUT_DIM   10
#define NPAD      50048        // 782 * 64 rows (gemm grid coverage)
#define ZROW      N_NODES      // dedicated all-zero row for bucket padding
#define NBINS     391          // bins of 128 nodes
#define CAP       64           // per-node degree cap (Poisson(16) tail ~1e-20)
#define LPAD      104          // LDS agg row stride: 208B = 13x16B

#define EBIN_BLOCKS 256
#define EPB2      (N_EDGES / EBIN_BLOCKS)             // 3125 edges/block
#define SEGSTR    3136                                // binned per-block stride (ints)
#define BINCAP    2816                                // packed csrc ints per bin (mean 2046+pad384, 8.6 sigma)

#define CAST_NB   ((N_NODES * 12 + 255) / 256)        // 2344
#define CONV_NB   ((3 * DIM * 2 * DIM + 255) / 256)   // 216

typedef __attribute__((ext_vector_type(8))) short          short8;
typedef __attribute__((ext_vector_type(8))) unsigned short u16x8;
typedef __attribute__((ext_vector_type(4))) float          f32x4;
typedef __attribute__((ext_vector_type(2))) float          f32x2;

__device__ __forceinline__ float b2f(unsigned short u) {
    union { unsigned int i; float f; } v; v.i = ((unsigned int)u) << 16; return v.f;
}
__device__ __forceinline__ unsigned short f2b(float f) {   // round-to-nearest-even
    union { float f; unsigned int i; } v; v.f = f;
    unsigned int u = v.i;
    return (unsigned short)((u + 0x7fffu + ((u >> 16) & 1u)) >> 16);
}

// ---------------------------------------------------------------------------
// OCP e4m3 shadow codec (shadow stores h*0.25).  HW cvt_pk path confirmed
// r6/r7; SW fallback guarded.
// ---------------------------------------------------------------------------
#if __has_builtin(__builtin_amdgcn_cvt_pk_f32_fp8) && __has_builtin(__builtin_amdgcn_cvt_pk_fp8_f32)
#define HW_FP8 1
#endif

__device__ __forceinline__ float d8s(unsigned int b) {     // SW decode (fallback)
    const unsigned int t = b & 0x7fu;
    union { unsigned int i; float f; } v;
    v.i = ((b & 0x80u) << 24) | ((t << 20) + (120u << 23));
    float sub = (float)(int)t * 0.001953125f;
    if (b & 0x80u) sub = -sub;
    return (t < 8u) ? sub : v.f;
}
__device__ __forceinline__ unsigned int e8s(float f) {     // SW encode (fallback)
    union { float f; unsigned int i; } v; v.f = f;
    const unsigned int u = v.i;
    const unsigned int s = (u >> 24) & 0x80u;
    const float af = fabsf(f);
    if (af < 0.015625f) {
        int mi = (int)(af * 512.f + 0.5f);
        return s | (unsigned int)(mi > 7 ? 7 : mi);
    }
    const unsigned int r = (u & 0x7fffffffu) + 0x0007ffffu + ((u >> 20) & 1u);
    const int ee = (int)(r >> 23) - 120;
    if (ee > 15) return s | 0x7eu;
    return s | ((unsigned int)ee << 3) | ((r >> 20) & 7u);
}

template<bool HI> __device__ __forceinline__ f32x2 dec_pk(unsigned int d) {
#ifdef HW_FP8
    return __builtin_amdgcn_cvt_pk_f32_fp8((int)d, HI);
#else
    const unsigned int w = HI ? (d >> 16) : (d & 0xffffu);
    f32x2 r; r[0] = d8s(w & 0xffu); r[1] = d8s(w >> 8);
    return r;
#endif
}
template<bool HI> __device__ __forceinline__ unsigned int enc_pk(float a, float b,
                                                                 unsigned int old) {
#ifdef HW_FP8
    return (unsigned int)__builtin_amdgcn_cvt_pk_fp8_f32(a, b, (int)old, HI);
#else
    const unsigned int p = e8s(a) | (e8s(b) << 8);
    return HI ? ((old & 0x0000ffffu) | (p << 16)) : ((old & 0xffff0000u) | p);
#endif
}

// ---------------------------------------------------------------------------
// Fused {edge binning (LDS-SORTED, coalesced dump) | cast x -> bf16 + fp8
// shadow | build Bt | zero-row + gr init}.
// r8 lesson: scattered 4-B global writes RMW whole 64-B lines (WRITE_SIZE
// 62.7 MB for 22 MB payload) and returning global atomics serialize (81us).
// Fix: per-block LDS count -> wave scan -> LDS scatter (sorted by bin) ->
// ONE contiguous 12.5 KB dump per block + coalesced cnt/ofs runs.  Zero
// scattered global writes anywhere in this kernel.
// ---------------------------------------------------------------------------
__global__ __launch_bounds__(256) void prep_pass1(
    const float* __restrict__ x,  const float* __restrict__ W1,
    const float* __restrict__ W2, const int* __restrict__ src,
    const int* __restrict__ dst,  unsigned short* __restrict__ harr,
    unsigned short* __restrict__ harrB,
    unsigned char* __restrict__ shA, unsigned char* __restrict__ shB,
    unsigned short* __restrict__ Bt, int* __restrict__ binned,
    int* __restrict__ cntG, int* __restrict__ ofsG, float* __restrict__ gr)
{
    __shared__ int cntL[NBINS];
    __shared__ int curL[NBINS];
    __shared__ int stag[EPB2];
    const int b = blockIdx.x;
    const int t = threadIdx.x;

    if (b < EBIN_BLOCKS) {
        const int e0 = b * EPB2;
        for (int i = t; i < NBINS; i += 256) cntL[i] = 0;
        __syncthreads();
        for (int i = t; i < EPB2; i += 256)
            atomicAdd(&cntL[dst[e0 + i] >> 7], 1);
        __syncthreads();
        // exclusive scan over 391 bins: wave 0, 7 bins/lane + shfl scan
        if (t < 64) {
            int vals[7]; int base = 0;
#pragma unroll
            for (int j = 0; j < 7; j++) {
                const int idx = t * 7 + j;
                vals[j] = (idx < NBINS) ? cntL[idx] : 0;
                base += vals[j];
            }
            int excl = base;
            for (int d = 1; d < 64; d <<= 1) {
                const int o = __shfl_up(excl, d);
                if (t >= d) excl += o;
            }
            excl -= base;
            int run = excl;
#pragma unroll
            for (int j = 0; j < 7; j++) {
                const int idx = t * 7 + j;
                if (idx < NBINS) curL[idx] = run;
                run += vals[j];
            }
        }
        __syncthreads();
        // cnt/ofs out (coalesced runs) BEFORE the scatter mutates curL
        for (int i = t; i < NBINS; i += 256) {
            cntG[b * NBINS + i] = cntL[i];
            ofsG[b * NBINS + i] = curL[i];
        }
        __syncthreads();
        // scatter edges into bin-sorted LDS staging
        for (int i = t; i < EPB2; i += 256) {
            const int d = dst[e0 + i];
            const int s = src[e0 + i];
            const int p = atomicAdd(&curL[d >> 7], 1);
            stag[p] = ((d & 127) << 16) | s;        // src < 65536
        }
        __syncthreads();
        // one contiguous coalesced dump
        for (int i = t; i < EPB2; i += 256)
            binned[(size_t)b * SEGSTR + i] = stag[i];
    } else if (b < EBIN_BLOCKS + CAST_NB) {
        const int tid = (b - EBIN_BLOCKS) * 256 + t;  // one per 8 cols
        if (tid >= N_NODES * 12) return;
        const int node = tid / 12;
        const int c    = (tid - node * 12) * 8;
        const float4 v0 = *(const float4*)(x + (size_t)node * DIM + c);
        const float4 v1 = *(const float4*)(x + (size_t)node * DIM + c + 4);
        u16x8 o;
        o[0] = f2b(v0.x); o[1] = f2b(v0.y); o[2] = f2b(v0.z); o[3] = f2b(v0.w);
        o[4] = f2b(v1.x); o[5] = f2b(v1.y); o[6] = f2b(v1.z); o[7] = f2b(v1.w);
        *(u16x8*)(harr + (size_t)node * DIM + c) = o;
        unsigned int da = 0u, db = 0u;
        da = enc_pk<false>(v0.x * 0.25f, v0.y * 0.25f, da);
        da = enc_pk<true >(v0.z * 0.25f, v0.w * 0.25f, da);
        db = enc_pk<false>(v1.x * 0.25f, v1.y * 0.25f, db);
        db = enc_pk<true >(v1.z * 0.25f, v1.w * 0.25f, db);
        uint2 ob; ob.x = da; ob.y = db;
        *(uint2*)(shA + (size_t)node * 96 + c) = ob;
    } else if (b < EBIN_BLOCKS + CAST_NB + CONV_NB) {
        const int idx = (b - EBIN_BLOCKS - CAST_NB) * 256 + t;  // Bt[l][n][k]
        if (idx >= 3 * DIM * 2 * DIM) return;
        const int l   = idx / (DIM * 2 * DIM);
        const int rem = idx - l * (DIM * 2 * DIM);
        const int n   = rem / (2 * DIM);
        const int k   = rem - n * (2 * DIM);
        const float v = (k < DIM) ? W1[(size_t)l * DIM * DIM + k * DIM + n]
                                  : W2[(size_t)l * DIM * DIM + (k - DIM) * DIM + n];
        Bt[idx] = f2b(v);
    } else {
        // zero-row init + gr zeroing
        if (t < 24) {
            u16x8 z;
#pragma unroll
            for (int i = 0; i < 8; i++) z[i] = 0;
            unsigned short* p = (t < 12) ? (harr  + (size_t)ZROW * DIM + t * 8)
                                         : (harrB + (size_t)ZROW * DIM + (t - 12) * 8);
            *(u16x8*)p = z;
        } else if (t < 48) {
            const int i = t - 24;
            uint2 z; z.x = 0u; z.y = 0u;
            unsigned char* p = (i < 12) ? (shA + (size_t)ZROW * 96 + i * 8)
                                        : (shB + (size_t)ZROW * 96 + (i - 12) * 8);
            *(uint2*)p = z;
        }
        float4* g4 = (float4*)gr;                 // 128*96 f32 = 3072 float4
#pragma unroll
        for (int i = 0; i < 12; i++) g4[t * 12 + i] = make_float4(0.f, 0.f, 0.f, 0.f);
    }
}

// ---------------------------------------------------------------------------
// Pass 2: one block per bin.  Gather the bin's 256 packed segments into LDS,
// node-sort in LDS (wave scans), then emit csrc as ONE contiguous packed run
// per bin (fully coalesced; padding to x4 with ZROW inline).  rowptr[n] =
// bin*BINCAP + packed offset replaces the old n*CAP bucket addressing.
// ---------------------------------------------------------------------------
__global__ __launch_bounds__(256) void pass2_build(
    const int* __restrict__ binned, const int* __restrict__ cntG,
    const int* __restrict__ ofsG,   int* __restrict__ csrc,
    int* __restrict__ deg,          int* __restrict__ rowptr)
{
    __shared__ int segcnt[EBIN_BLOCKS], segofs[EBIN_BLOCKS], segdst[EBIN_BLOCKS];
    __shared__ int stag[BINCAP];
    __shared__ int stag2[BINCAP];
    __shared__ int ncnt[128];
    __shared__ int npos[129], ppos[129];
    __shared__ int totalL;

    const int bin = blockIdx.x;
    const int t   = threadIdx.x;
    const int n0  = bin << 7;

    segcnt[t] = cntG[t * NBINS + bin];
    segofs[t] = ofsG[t * NBINS + bin];
    if (t < 128) ncnt[t] = 0;
    __syncthreads();

    // exclusive scan of 256 segment counts (wave 0, 4/lane)
    if (t < 64) {
        const int i0 = t * 4;
        const int v0 = segcnt[i0], v1 = segcnt[i0 + 1];
        const int v2 = segcnt[i0 + 2], v3 = segcnt[i0 + 3];
        int base = v0 + v1 + v2 + v3;
        int excl = base;
        for (int d = 1; d < 64; d <<= 1) {
            const int o = __shfl_up(excl, d);
            if (t >= d) excl += o;
        }
        excl -= base;
        segdst[i0]     = excl;
        segdst[i0 + 1] = excl + v0;
        segdst[i0 + 2] = excl + v0 + v1;
        segdst[i0 + 3] = excl + v0 + v1 + v2;
        if (t == 63) totalL = excl + base;
    }
    __syncthreads();
    const int total = min(totalL, BINCAP);

    // gather this bin's segment from each source block (scattered READS, L2)
    {
        const int c = segcnt[t];
        const int* __restrict__ sp = binned + (size_t)t * SEGSTR + segofs[t];
        const int d0 = segdst[t];
        for (int j = 0; j < c; j++)
            if (d0 + j < BINCAP) stag[d0 + j] = sp[j];
    }
    __syncthreads();

    // per-node counts
    for (int i = t; i < total; i += 256)
        atomicAdd(&ncnt[stag[i] >> 16], 1);
    __syncthreads();

    // node scans: packed (dn in low16 | dp in high16), wave 0, 2 nodes/lane
    if (t < 64) {
        const int c0 = min(ncnt[t * 2], CAP), c1 = min(ncnt[t * 2 + 1], CAP);
        const int q0 = (c0 + 3) & ~3,         q1 = (c1 + 3) & ~3;
        const int basep = c0 + c1, baseq = q0 + q1;
        int pack = basep | (baseq << 16);
        int excl = pack;
        for (int d = 1; d < 64; d <<= 1) {
            const int o = __shfl_up(excl, d);
            if (t >= d) excl += o;
        }
        excl -= pack;
        const int ep = excl & 0xffff;
        const int eq = ((unsigned int)excl) >> 16;
        npos[t * 2] = ep; npos[t * 2 + 1] = ep + c0;
        ppos[t * 2] = eq; ppos[t * 2 + 1] = eq + q0;
        if (t == 63) { npos[128] = ep + basep; ppos[128] = eq + baseq; }
    }
    __syncthreads();

    if (t < 128 && n0 + t < N_NODES) {
        deg[n0 + t]    = ppos[t + 1] - ppos[t];           // padded degree (x4)
        rowptr[n0 + t] = bin * BINCAP + ppos[t];
    }
    if (t < 128) ncnt[t] = 0;                             // reuse as cursor
    __syncthreads();

    // node-sort into stag2 (packed by dn)
    for (int i = t; i < total; i += 256) {
        const int v  = stag[i];
        const int n  = v >> 16;
        const int p  = atomicAdd(&ncnt[n], 1);
        const int dn = npos[n + 1] - npos[n];
        if (p < dn) stag2[npos[n] + p] = v & 0xffff;
    }
    __syncthreads();

    // contiguous coalesced padded output
    const int P = ppos[128];
    for (int i = t; i < P; i += 256) {
        int lo = 0, hi = 128;                              // largest n: ppos[n] <= i
        while (lo + 1 < hi) { const int mid = (lo + hi) >> 1; if (ppos[mid] <= i) lo = mid; else hi = mid; }
        const int slot = i - ppos[lo];
        const int dn   = npos[lo + 1] - npos[lo];
        csrc[(size_t)bin * BINCAP + i] = (slot < dn) ? stag2[npos[lo] + slot] : ZROW;
    }
}

// ---------------------------------------------------------------------------
// Fused layer, 384 threads, template<LAST> (r7 structure, 44.4us/layer).
// Gather reads the fp8 shadow (96 B/row, 6 lanes x one 16B load) with HW
// cvt_pk_f32_fp8 decode; shadow holds h*0.25 (x4 at LDS write).  Bucket
// addressing now via rowptr (packed csrc).  Phase 2: mfma_f32_16x16x32_bf16,
// A-frag A[m=lane&15][k=quad*8+j], C/D col=lane&15,row=quad*4+reg (m89).
// LAST fuses pooling: run-length merge by graph id -> spread atomicAdd gr.
// ---------------------------------------------------------------------------
#define LOAD4(x0,x1,x2,x3,base) do {                                        \
    const int4 sI = *(const int4*)(bkt + (base));                           \
    x0 = *(const uint4*)(hb + (size_t)sI.x * 96);                           \
    x1 = *(const uint4*)(hb + (size_t)sI.y * 96);                           \
    x2 = *(const uint4*)(hb + (size_t)sI.z * 96);                           \
    x3 = *(const uint4*)(hb + (size_t)sI.w * 96);                           \
} while (0)

#define ACCD(dw, b0) do {                                                   \
    const f32x2 lo_ = dec_pk<false>(dw);                                    \
    const f32x2 hi_ = dec_pk<true >(dw);                                    \
    a[(b0) + 0] += lo_[0]; a[(b0) + 1] += lo_[1];                           \
    a[(b0) + 2] += hi_[0]; a[(b0) + 3] += hi_[1];                           \
} while (0)
#define ACC1(vv) do { ACCD(vv.x, 0); ACCD(vv.y, 4); ACCD(vv.z, 8); ACCD(vv.w, 12); } while (0)
#define ACC4(x0,x1,x2,x3) do { ACC1(x0); ACC1(x1); ACC1(x2); ACC1(x3); } while (0)

template<bool LAST>
__global__ __launch_bounds__(384) void gnn_layer(
    const unsigned short* __restrict__ harr, const int* __restrict__ deg,
    const int* __restrict__ rowptr, const int* __restrict__ csrc,
    const unsigned short* __restrict__ Btl,
    unsigned short* __restrict__ hout,
    const unsigned char* __restrict__ shIn, unsigned char* __restrict__ shOut,
    const int* __restrict__ batch, float* __restrict__ gr)
{
    __shared__ unsigned short aggLds[64][LPAD];
    __shared__ int batchLds[64];
    const int t       = threadIdx.x;
    const int rowBase = blockIdx.x * 64;

    const int lane = t & 63;
    const int w    = t >> 6;    // 0..5 col tile
    const int m    = lane & 15;
    const int q    = lane >> 4;

    if constexpr (LAST) {
        if (t < 64)
            batchLds[t] = (rowBase + t < N_NODES) ? batch[rowBase + t] : -1;
    }

    // hoisted B fragments (overlap with gather)
    short8 bfrag[6];
#pragma unroll
    for (int s = 0; s < 6; s++)
        bfrag[s] = *(const short8*)(Btl + (size_t)(w * 16 + m) * (2 * DIM) + s * 32 + q * 8);

    // ---- phase 1: gather from fp8 shadow (6 lanes x 16B = one 96B row) ----
    {
        const int r    = t / 6;          // 0..63
        const int sub  = t - r * 6;      // 0..5
        const int node = rowBase + r;
        const int off  = sub * 16;       // 16 cols = 16 B (fp8) = 16 elems (LDS)

        float a[16];
#pragma unroll
        for (int i = 0; i < 16; i++) a[i] = 0.f;

        if (node < N_NODES) {
            const int nb = deg[node] >> 2;          // padded: full batches only
            const int* __restrict__ bkt = csrc + rowptr[node];
            const unsigned char* __restrict__ hb = shIn + off;

            uint4 va0, va1, va2, va3;   // set A
            uint4 wa0, wa1, wa2, wa3;   // set B

            if (nb > 0) {
                LOAD4(va0, va1, va2, va3, 0);
                int b = 1;
                for (; b + 1 < nb; b += 2) {
                    LOAD4(wa0, wa1, wa2, wa3, b * 4);
                    ACC4(va0, va1, va2, va3);
                    LOAD4(va0, va1, va2, va3, (b + 1) * 4);
                    ACC4(wa0, wa1, wa2, wa3);
                }
                if (b < nb) {
                    LOAD4(wa0, wa1, wa2, wa3, b * 4);
                    ACC4(va0, va1, va2, va3);
                    ACC4(wa0, wa1, wa2, wa3);
                } else {
                    ACC4(va0, va1, va2, va3);
                }
            }
        }

        u16x8 o0, o1;
#pragma unroll
        for (int i = 0; i < 8; i++) {
            o0[i] = f2b(a[i] * 4.f);            // undo the /4 shadow scale once
            o1[i] = f2b(a[i + 8] * 4.f);
        }
        *(u16x8*)(&aggLds[r][off])     = o0;
        *(u16x8*)(&aggLds[r][off + 8]) = o1;
    }
    __syncthreads();

    // ---- phase 2: MFMA (all accs first; aggLds still holds the agg tile) ----
    f32x4 accv[4];
#pragma unroll
    for (int r = 0; r < 4; r++) {
        const int rb = rowBase + r * 16;
        f32x4 acc = {0.f, 0.f, 0.f, 0.f};
        const unsigned short* ah = harr + (size_t)(rb + m) * DIM + q * 8;
#pragma unroll
        for (int s = 0; s < 3; s++) {
            const short8 af = *(const short8*)(ah + s * 32);
            acc = __builtin_amdgcn_mfma_f32_16x16x32_bf16(af, bfrag[s], acc, 0, 0, 0);
        }
#pragma unroll
        for (int s = 0; s < 3; s++) {
            const short8 af = *(const short8*)(&aggLds[r * 16 + m][s * 32 + q * 8]);
            acc = __builtin_amdgcn_mfma_f32_16x16x32_bf16(af, bfrag[s + 3], acc, 0, 0, 0);
        }
        accv[r] = acc;
    }

    if constexpr (LAST) {
        // ---- fused pooling: run-length merge by graph, then atomicAdd ----
        const int col = w * 16 + m;
        int   curg = -1;
        float sum  = 0.f;
#pragma unroll
        for (int r = 0; r < 4; r++) {
#pragma unroll
            for (int i = 0; i < 4; i++) {
                const int g = batchLds[r * 16 + q * 4 + i];
                const float v = fmaxf(accv[r][i], 0.f);
                if (g < 0) {
                    if (curg >= 0) { atomicAdd(&gr[curg * DIM + col], sum); curg = -1; }
                } else if (g != curg) {
                    if (curg >= 0) atomicAdd(&gr[curg * DIM + col], sum);
                    curg = g; sum = v;
                } else {
                    sum += v;
                }
            }
        }
        if (curg >= 0) atomicAdd(&gr[curg * DIM + col], sum);
    } else {
        __syncthreads();        // all aggLds reads done; safe to overwrite

        // ---- epilogue: acc -> LDS -> coalesced bf16 + fp8 shadow stores ----
#pragma unroll
        for (int r = 0; r < 4; r++)
#pragma unroll
            for (int i = 0; i < 4; i++)
                aggLds[r * 16 + q * 4 + i][w * 16 + m] = f2b(fmaxf(accv[r][i], 0.f));
        __syncthreads();

#pragma unroll
        for (int k = 0; k < 2; k++) {
            const int idx = t + k * 384;     // 768 chunks: 64 rows x 12 x 16B
            const int row = idx / 12;
            const int ch  = idx - row * 12;
            const int grow = rowBase + row;
            if (grow < N_NODES)
                *(u16x8*)(hout + (size_t)grow * DIM + ch * 8)
                    = *(const u16x8*)(&aggLds[row][ch * 8]);
        }
        {
            const int row  = t / 6;          // 384 chunks: 64 rows x 6 x 16 cols
            const int ch   = t - row * 6;
            const int grow = rowBase + row;
            if (grow < N_NODES) {
                const u16x8 h0 = *(const u16x8*)(&aggLds[row][ch * 16]);
                const u16x8 h1 = *(const u16x8*)(&aggLds[row][ch * 16 + 8]);
                unsigned int d0 = 0u, d1 = 0u, d2 = 0u, d3 = 0u;
                d0 = enc_pk<false>(b2f(h0[0]) * 0.25f, b2f(h0[1]) * 0.25f, d0);
                d0 = enc_pk<true >(b2f(h0[2]) * 0.25f, b2f(h0[3]) * 0.25f, d0);
                d1 = enc_pk<false>(b2f(h0[4]) * 0.25f, b2f(h0[5]) * 0.25f, d1);
                d1 = enc_pk<true >(b2f(h0[6]) * 0.25f, b2f(h0[7]) * 0.25f, d1);
                d2 = enc_pk<false>(b2f(h1[0]) * 0.25f, b2f(h1[1]) * 0.25f, d2);
                d2 = enc_pk<true >(b2f(h1[2]) * 0.25f, b2f(h1[3]) * 0.25f, d2);
                d3 = enc_pk<false>(b2f(h1[4]) * 0.25f, b2f(h1[5]) * 0.25f, d3);
                d3 = enc_pk<true >(b2f(h1[6]) * 0.25f, b2f(h1[7]) * 0.25f, d3);
                uint4 ob; ob.x = d0; ob.y = d1; ob.z = d2; ob.w = d3;
                *(uint4*)(shOut + (size_t)grow * 96 + ch * 16) = ob;
            }
        }
    }
}

// ---------------------------------------------------------------------------
// Tiny classifier on the pooled gr[128][96] (pooling fused into layer 3).
// ---------------------------------------------------------------------------
__global__ __launch_bounds__(128) void classify(
    const float* __restrict__ gr,
    const float* __restrict__ cw1, const float* __restrict__ cb1,
    const float* __restrict__ cw2, const float* __restrict__ cb2,
    float* __restrict__ out)
{
    const int g = blockIdx.x;
    const int t = threadIdx.x;

    __shared__ float grs[DIM];
    __shared__ float hid[DIM];

    if (t < DIM) grs[t] = gr[g * DIM + t];
    __syncthreads();

    if (t < DIM) {
        float hsum = cb1[t];
#pragma unroll 8
        for (int k = 0; k < DIM; k++) hsum += grs[k] * cw1[k * DIM + t];
        hid[t] = fmaxf(hsum, 0.f);
    }
    __syncthreads();

    if (t < OUT_DIM) {
        float o = cb2[t];
#pragma unroll 8
        for (int k = 0; k < DIM; k++) o += hid[k] * cw2[k * OUT_DIM + t];
        out[g * OUT_DIM + t] = o;
    }
}

// ---------------------------------------------------------------------------
extern "C" void kernel_launch(void* const* d_in, const int* in_sizes, int n_in,
                              void* d_out, int out_size, void* d_ws, size_t ws_size,
                              hipStream_t stream)
{
    const float* x     = (const float*)d_in[0];
    const int*   ei    = (const int*)  d_in[1];
    const int*   batch = (const int*)  d_in[2];
    const float* W1    = (const float*)d_in[3];
    const float* W2    = (const float*)d_in[4];
    const float* cw1   = (const float*)d_in[5];
    const float* cb1   = (const float*)d_in[6];
    const float* cw2   = (const float*)d_in[7];
    const float* cb2   = (const float*)d_in[8];
    float*       out   = (float*)d_out;

    const int* src = ei;             // edge_index[0]
    const int* dst = ei + N_EDGES;   // edge_index[1]

    // workspace layout (16B-aligned at each boundary)
    unsigned short* bufA = (unsigned short*)d_ws;          // [NPAD,96] bf16
    unsigned short* bufB = bufA + (size_t)NPAD * DIM;      // [NPAD,96] bf16
    unsigned short* Bt   = bufB + (size_t)NPAD * DIM;      // [3,96,192] bf16
    int*   binned = (int*)(Bt + 3 * DIM * 2 * DIM);        // [256*SEGSTR]
    int*   cntG   = binned + (size_t)EBIN_BLOCKS * SEGSTR; // [256*NBINS]
    int*   ofsG   = cntG + EBIN_BLOCKS * NBINS;            // [256*NBINS]
    int*   csrc   = ofsG + EBIN_BLOCKS * NBINS;            // [NBINS*BINCAP] packed
    int*   deg    = csrc + (size_t)NBINS * BINCAP;         // [N] padded degree
    int*   rowptr = deg + N_NODES;                         // [N]
    unsigned char* shA = (unsigned char*)(rowptr + N_NODES); // [(N+1)*96] fp8
    unsigned char* shB = shA + (size_t)(N_NODES + 1) * 96;   // [(N+1)*96] fp8
    float* gr = (float*)(shB + (size_t)(N_NODES + 1) * 96);  // [128,96] f32

    prep_pass1<<<EBIN_BLOCKS + CAST_NB + CONV_NB + 1, 256, 0, stream>>>(
        x, W1, W2, src, dst, bufA, bufB, shA, shB, Bt, binned, cntG, ofsG, gr);
    pass2_build<<<NBINS, 256, 0, stream>>>(binned, cntG, ofsG, csrc, deg, rowptr);

    gnn_layer<false><<<NPAD / 64, 384, 0, stream>>>(bufA, deg, rowptr, csrc, Bt,
                                                    bufB, shA, shB, batch, gr);
    gnn_layer<false><<<NPAD / 64, 384, 0, stream>>>(bufB, deg, rowptr, csrc,
                                                    Bt + (size_t)DIM * 2 * DIM,
                                                    bufA, shB, shA, batch, gr);
    gnn_layer<true><<<NPAD / 64, 384, 0, stream>>>(bufA, deg, rowptr, csrc,
                                                   Bt + (size_t)2 * DIM * 2 * DIM,
                                                   bufB, shA, shB, batch, gr);

    classify<<<N_GRAPHS, 128, 0, stream>>>(gr, cw1, cb1, cw2, cb2, out);
}